// Round 11
// baseline (543.109 us; speedup 1.0000x reference)
//
#include <hip/hip_runtime.h>
#include <hip/hip_bf16.h>

#define LRELU(v) ((v) > 0.0f ? (v) : 0.01f * (v))
#define EPS 0.1f

#define BIN_EPB 2048        // edges per k_bin block
#define BIN_CAP 12288       // bucket capacity (expected 8163, +45 sigma headroom)

// fast tanh via v_exp_f32 + v_rcp_f32: ~1e-7 abs err, saturates correctly
__device__ __forceinline__ float fast_tanh(float v)
{
    float e = __expf(2.0f * v);
    return 1.0f - 2.0f * __builtin_amdgcn_rcpf(e + 1.0f);
}

// bf16 <-> f32 (RNE pack); feature rows stored bf16 to halve gather traffic
__device__ __forceinline__ float bf2f(unsigned short h)
{
    return __uint_as_float(((unsigned int)h) << 16);
}
__device__ __forceinline__ unsigned short f2bf(float f)
{
    unsigned int u = __float_as_uint(f);
    u += 0x7FFFu + ((u >> 16) & 1u);
    return (unsigned short)(u >> 16);
}

// ---------------------------------------------------------------------------
// K1: per-node feature MLP, thread-per-node. Weight accesses wave-uniform ->
// SGPR path; mid[64] in VGPRs; ILP-4 fma chains. Fuses al/ar dots.
// __launch_bounds__(256,2): ~130 live VGPRs; without it the allocator capped
// at 64 VGPRs and spilled ~400 MB to scratch (round-9 regression).
// ---------------------------------------------------------------------------
__global__ void __launch_bounds__(256, 2)
k_feat(const float* __restrict__ num_prop,
       const float* __restrict__ cat_prop,
       const float* __restrict__ W_num, const float* __restrict__ b_num,
       const float* __restrict__ W_cat, const float* __restrict__ b_cat,
       const float* __restrict__ W_tog, const float* __restrict__ b_tog,
       const float* __restrict__ att_l, const float* __restrict__ att_r,
       unsigned short* __restrict__ xb,
       float* __restrict__ al, float* __restrict__ ar, int N)
{
    int n = blockIdx.x * blockDim.x + threadIdx.x;
    if (n >= N) return;

    float num[20], cat[12];
    {
        const float* np_ = num_prop + (size_t)n * 20;
        #pragma unroll
        for (int k = 0; k < 20; k++) num[k] = np_[k];
        const float* cp = cat_prop + (size_t)n * 12;
        #pragma unroll
        for (int k = 0; k < 12; k++) cat[k] = cp[k];
    }

    float mid[64];
    #pragma unroll
    for (int j = 0; j < 32; j++) {
        float s = b_num[j];
        #pragma unroll
        for (int k = 0; k < 20; k++) s = fmaf(num[k], W_num[k * 32 + j], s);
        mid[j] = LRELU(s);
    }
    #pragma unroll
    for (int j = 0; j < 32; j++) {
        float s = b_cat[j];
        #pragma unroll
        for (int k = 0; k < 12; k++) s = fmaf(cat[k], W_cat[k * 32 + j], s);
        mid[32 + j] = LRELU(s);
    }

    float al_acc = 0.0f, ar_acc = 0.0f;
    unsigned short* xbrow = xb + (size_t)n * 64;
    for (int j0 = 0; j0 < 64; j0 += 4) {     // 16 iterations (code size)
        float o[4];
        #pragma unroll
        for (int jj = 0; jj < 4; jj++) {
            int j = j0 + jj;
            float s = b_tog[j];
            #pragma unroll
            for (int k = 0; k < 64; k++) s = fmaf(mid[k], W_tog[k * 64 + j], s);
            s = LRELU(s);
            o[jj] = s;
            al_acc = fmaf(s, att_l[j], al_acc);
            ar_acc = fmaf(s, att_r[j], ar_acc);
        }
        *(ushort4*)(xbrow + j0) = make_ushort4(f2bf(o[0]), f2bf(o[1]),
                                               f2bf(o[2]), f2bf(o[3]));  // ws: aligned
    }
    al[n] = al_acc;
    ar[n] = ar_acc;
}

// ---------------------------------------------------------------------------
// K2: radix partition phase 1 (+ deg histogram folded in).
// ---------------------------------------------------------------------------
__global__ void k_bin(const int* __restrict__ src, const int* __restrict__ dst,
                      int* __restrict__ deg, int* __restrict__ bucket_cnt,
                      int2* __restrict__ buckets, int E, int NB)
{
    __shared__ int  hist[256];
    __shared__ int  lbase[256];
    __shared__ int  gbase[256];
    __shared__ int2 stage[BIN_EPB];

    int tid  = threadIdx.x;          // blockDim = 256
    int base = blockIdx.x * BIN_EPB;

    hist[tid] = 0;
    __syncthreads();

    int s[8], d[8], rk[8];
    #pragma unroll
    for (int k = 0; k < 8; k++) {
        int e = base + k * 256 + tid;
        s[k] = -1;
        if (e < E) {
            s[k] = src[e];
            d[k] = dst[e];
            atomicAdd(&deg[d[k]], 1);
            rk[k] = atomicAdd(&hist[d[k] >> 10], 1);
        }
    }
    __syncthreads();

    int v = hist[tid];
    lbase[tid] = v;
    __syncthreads();
    for (int off = 1; off < 256; off <<= 1) {
        int t = (tid >= off) ? lbase[tid - off] : 0;
        __syncthreads();
        lbase[tid] += t;
        __syncthreads();
    }
    int incl = lbase[tid];
    __syncthreads();
    lbase[tid] = incl - v;
    if (tid < NB && v > 0) gbase[tid] = atomicAdd(&bucket_cnt[tid], v);
    __syncthreads();

    #pragma unroll
    for (int k = 0; k < 8; k++) {
        if (s[k] >= 0) {
            int b = d[k] >> 10;
            stage[lbase[b] + rk[k]] = make_int2(s[k], d[k]);
        }
    }
    __syncthreads();

    int tot = min(BIN_EPB, E - base);
    for (int i = tid; i < tot; i += 256) {
        int2 p = stage[i];
        int b = p.y >> 10;
        buckets[(size_t)b * BIN_CAP + gbase[b] + (i - lbase[b])] = p;
    }
}

// ---------------------------------------------------------------------------
// CSR scan over PADDED row lengths ((deg+7)&~7).
// ---------------------------------------------------------------------------
__global__ void k_scan1(const int* __restrict__ deg, int* __restrict__ row_start,
                        int* __restrict__ blockSums, int N)
{
    __shared__ int sh[1024];
    int tid = threadIdx.x;
    int i = blockIdx.x * 1024 + tid;
    int v = (i < N) ? ((deg[i] + 7) & ~7) : 0;      // padded length
    sh[tid] = v;
    __syncthreads();
    #pragma unroll
    for (int off = 1; off < 1024; off <<= 1) {
        int t = (tid >= off) ? sh[tid - off] : 0;
        __syncthreads();
        sh[tid] += t;
        __syncthreads();
    }
    if (i < N) row_start[i] = sh[tid] - v;          // exclusive within block
    if (tid == 1023) blockSums[blockIdx.x] = sh[1023];
}

__global__ void k_scan2(int* __restrict__ blockSums, int nb)
{
    __shared__ int sh[256];
    int tid = threadIdx.x;
    int v = (tid < nb) ? blockSums[tid] : 0;
    sh[tid] = v;
    __syncthreads();
    #pragma unroll
    for (int off = 1; off < 256; off <<= 1) {
        int t = (tid >= off) ? sh[tid - off] : 0;
        __syncthreads();
        sh[tid] += t;
        __syncthreads();
    }
    if (tid < nb) blockSums[tid] = sh[tid] - v;     // exclusive
}

// row_start += block offset; pack ald1 = {al, rsqrt(deg+1)}
__global__ void k_scan3(int* __restrict__ row_start, const int* __restrict__ blockSums,
                        const int* __restrict__ deg,
                        const float* __restrict__ al, float2* __restrict__ ald1, int N)
{
    int i = blockIdx.x * blockDim.x + threadIdx.x;
    if (i >= N) return;
    row_start[i] += blockSums[i >> 10];
    float dv = 1.0f / sqrtf((float)deg[i] + 1.0f);   // +1 self-loop
    ald1[i]  = make_float2(al[i], dv);
}

// ---------------------------------------------------------------------------
// K4: radix partition phase 2: bucket-local CSR fill (LDS cursors). Also
// stores dsts[] so the alpha kernels can run edge-parallel in CSR order.
// ---------------------------------------------------------------------------
__global__ void k_fill2(const int2* __restrict__ buckets, const int* __restrict__ bucket_cnt,
                        const int* __restrict__ row_start,
                        int* __restrict__ srcs, int* __restrict__ dsts)
{
    __shared__ int cur[1024];
    int b   = blockIdx.x;
    int tid = threadIdx.x;          // blockDim = 1024
    cur[tid] = 0;
    __syncthreads();

    int cnt = bucket_cnt[b];
    const int2* bp = buckets + (size_t)b * BIN_CAP;
    for (int i = tid; i < cnt; i += 1024) {
        int2 p = bp[i];
        int r = p.y & 1023;
        int o = atomicAdd(&cur[r], 1);
        int pos = row_start[p.y] + o;
        srcs[pos] = p.x;
        dsts[pos] = p.y;
    }
}

// ---------------------------------------------------------------------------
// K4b: edge-parallel alpha in CSR order: alphas[p] = tanh(al[s]+ar[d])*dinv[s]*dinv[d]
// Padding slots (src = -1) get alpha = 0; dsts never read there.
// ---------------------------------------------------------------------------
__global__ void k_alphaE(const int* __restrict__ srcs, const int* __restrict__ dsts,
                         const float2* __restrict__ ald, const float* __restrict__ arr,
                         float* __restrict__ alphas, int P)
{
    int p = blockIdx.x * blockDim.x + threadIdx.x;
    if (p >= P) return;
    int s = srcs[p];
    float a = 0.0f;
    if (s >= 0) {
        int d = dsts[p];
        float2 as = ald[s];
        float2 ad = ald[d];
        a = fast_tanh(as.x + arr[d]) * as.y * ad.y;
    }
    alphas[p] = a;
}

// ---------------------------------------------------------------------------
// K5: gather layer 1. n is readfirstlane'd -> wave-uniform: srcs/alphas loads
// become s_load (scalar pipe), row address arith is SALU, per-edge VALU is
// load+cvt+fma with alpha as the fma's SGPR operand. Rows padded to x8.
// Fused finalize + al2/ar2 reductions; epilogue packs ald2 = {al2, dinv}.
// ---------------------------------------------------------------------------
__global__ void k_gather1(const int* __restrict__ srcs, const float* __restrict__ alphas,
                          const int* __restrict__ row_start, const int* __restrict__ deg,
                          const unsigned short* __restrict__ xb,
                          const float2* __restrict__ ald1, const float* __restrict__ ar,
                          const float* __restrict__ att_l, const float* __restrict__ att_r,
                          unsigned short* __restrict__ h1b, float2* __restrict__ ald2,
                          float* __restrict__ ar2, int N)
{
    int lane = threadIdx.x & 63;
    int n    = __builtin_amdgcn_readfirstlane(blockIdx.x * 4 + (threadIdx.x >> 6));
    if (n >= N) return;

    int    s0   = row_start[n];
    int    cnt  = deg[n];
    int    cntp = (cnt + 7) & ~7;
    float2 self = ald1[n];          // {al[n], dinv[n]}
    float  di   = self.y;
    float  arn  = ar[n];

    float acc = 0.0f;
    for (int j = 0; j < cntp; j += 8) {
        int sv[8]; float av[8], vv[8];
        #pragma unroll
        for (int t = 0; t < 8; t++) {
            sv[t] = max(srcs[s0 + j + t], 0);     // scalar: padding -> row 0
            av[t] = alphas[s0 + j + t];           // scalar: padding -> 0
        }
        #pragma unroll
        for (int t = 0; t < 8; t++) vv[t] = bf2f(xb[(size_t)sv[t] * 64 + lane]);
        #pragma unroll
        for (int t = 0; t < 8; t++) acc = fmaf(vv[t], av[t], acc);
    }

    float selfa = fast_tanh(self.x + arn) * di * di;
    float xnl   = bf2f(xb[(size_t)n * 64 + lane]);
    float v     = acc + (selfa + EPS) * xnl;

    float pl = v * att_l[lane];
    float pr = v * att_r[lane];
    #pragma unroll
    for (int off = 32; off > 0; off >>= 1) {
        pl += __shfl_down(pl, off);
        pr += __shfl_down(pr, off);
    }
    h1b[(size_t)n * 64 + lane] = f2bf(v);
    if (lane == 0) { ald2[n] = make_float2(pl, di); ar2[n] = pr; }
}

// ---------------------------------------------------------------------------
// K6: gather layer 2 (h = h1 bf16, h0 = x bf16), same scalar-offload
// structure, fused finalize + abs-smooth; x2 written fp32.
// ---------------------------------------------------------------------------
__global__ void k_gather2(const int* __restrict__ srcs, const float* __restrict__ alphas,
                          const int* __restrict__ row_start, const int* __restrict__ deg,
                          const unsigned short* __restrict__ h1b,
                          const unsigned short* __restrict__ xb,
                          const float2* __restrict__ ald2, const float* __restrict__ ar2,
                          float* __restrict__ x2, int N)
{
    int lane = threadIdx.x & 63;
    int n    = __builtin_amdgcn_readfirstlane(blockIdx.x * 4 + (threadIdx.x >> 6));
    if (n >= N) return;

    int    s0   = row_start[n];
    int    cnt  = deg[n];
    int    cntp = (cnt + 7) & ~7;
    float2 self = ald2[n];          // {al2[n], dinv[n]}
    float  di   = self.y;
    float  arn  = ar2[n];

    float acc = 0.0f;
    for (int j = 0; j < cntp; j += 8) {
        int sv[8]; float av[8], vv[8];
        #pragma unroll
        for (int t = 0; t < 8; t++) {
            sv[t] = max(srcs[s0 + j + t], 0);
            av[t] = alphas[s0 + j + t];
        }
        #pragma unroll
        for (int t = 0; t < 8; t++) vv[t] = bf2f(h1b[(size_t)sv[t] * 64 + lane]);
        #pragma unroll
        for (int t = 0; t < 8; t++) acc = fmaf(vv[t], av[t], acc);
    }

    float selfa = fast_tanh(self.x + arn) * di * di;
    float h1l   = bf2f(h1b[(size_t)n * 64 + lane]);
    float xnl   = bf2f(xb[(size_t)n * 64 + lane]);
    float v = acc + selfa * h1l + EPS * xnl;
    x2[(size_t)n * 64 + lane] = sqrtf(v * v + 1e-8f);
}

// ---------------------------------------------------------------------------
// K7: per-user CSR segment sum
// ---------------------------------------------------------------------------
__global__ void k_usersum(const float* __restrict__ x2, const int* __restrict__ offs,
                          float* __restrict__ x3, int U)
{
    int u    = blockIdx.x;
    int lane = threadIdx.x;
    if (u >= U) return;
    int s = offs[u], e = offs[u + 1];
    float acc = 0.0f;
    for (int n = s; n < e; n++) acc += x2[(size_t)n * 64 + lane];
    x3[(size_t)u * 64 + lane] = acc;
}

// ---------------------------------------------------------------------------
// K8: head
// ---------------------------------------------------------------------------
__global__ void k_head(const float* __restrict__ x3, const int* __restrict__ re_index,
                       const float* __restrict__ W_f1, const float* __restrict__ b_f1,
                       const float* __restrict__ W_lab, const float* __restrict__ b_lab,
                       float* __restrict__ out, int U)
{
    int u = blockIdx.x * blockDim.x + threadIdx.x;
    if (u >= U) return;
    int r = re_index[u];
    const float* y = x3 + (size_t)r * 64;
    float yv[64];
    #pragma unroll
    for (int k = 0; k < 64; k++) yv[k] = y[k];
    float o0 = b_lab[0], o1 = b_lab[1];
    for (int j = 0; j < 32; j++) {
        float s = b_f1[j];
        #pragma unroll 8
        for (int k = 0; k < 64; k++) s = fmaf(yv[k], W_f1[k * 32 + j], s);
        s = LRELU(s);
        o0 = fmaf(s, W_lab[j * 2 + 0], o0);
        o1 = fmaf(s, W_lab[j * 2 + 1], o1);
    }
    out[(size_t)u * 2 + 0] = o0;
    out[(size_t)u * 2 + 1] = o1;
}

// ---------------------------------------------------------------------------
extern "C" void kernel_launch(void* const* d_in, const int* in_sizes, int n_in,
                              void* d_out, int out_size, void* d_ws, size_t ws_size,
                              hipStream_t stream)
{
    const float* num_prop = (const float*)d_in[0];
    const float* cat_prop = (const float*)d_in[1];
    const int*   offs     = (const int*)d_in[2];
    const int*   edge     = (const int*)d_in[3];
    const int*   re_index = (const int*)d_in[4];
    const float* W_num    = (const float*)d_in[5];
    const float* b_num    = (const float*)d_in[6];
    const float* W_cat    = (const float*)d_in[7];
    const float* b_cat    = (const float*)d_in[8];
    const float* W_tog    = (const float*)d_in[9];
    const float* b_tog    = (const float*)d_in[10];
    const float* att_l    = (const float*)d_in[11];
    const float* att_r    = (const float*)d_in[12];
    const float* W_f1     = (const float*)d_in[13];
    const float* b_f1     = (const float*)d_in[14];
    const float* W_lab    = (const float*)d_in[15];
    const float* b_lab    = (const float*)d_in[16];

    const int N = in_sizes[0] / 20;
    const int E = in_sizes[3] / 2;
    const int U = in_sizes[4];

    const int* src = edge;       // edge_index[0]
    const int* dst = edge + E;   // edge_index[1]

    const int    NB      = (N + 1023) >> 10;                   // dst buckets
    const size_t srcsCap = (size_t)E + 7ull * (size_t)N + 64;  // padded CSR capacity

    // workspace carve-up (4-byte units; int2/float2/ushort4 8B-aligned by layout)
    float* ws = (float*)d_ws;
    size_t off = 0;
    unsigned short* xb  = (unsigned short*)(ws + off); off += (size_t)N * 32;  // bf16 x
    unsigned short* h1b = (unsigned short*)(ws + off); off += (size_t)N * 32;  // bf16 h1
    float*  B    = ws + off; off += (size_t)N * 64;   // x2 (fp32)
    float2* ald1 = (float2*)(ws + off); off += (size_t)N * 2;
    float2* ald2 = (float2*)(ws + off); off += (size_t)N * 2;
    int2*   buckets = (int2*)(ws + off); off += (size_t)NB * BIN_CAP * 2;
    float*  al   = ws + off; off += N;
    float*  ar   = ws + off; off += N;
    float*  ar2  = ws + off; off += N;
    float*  x3   = ws + off; off += (size_t)U * 64;
    int*    deg        = (int*)(ws + off); off += N;
    int*    row_start  = (int*)(ws + off); off += N;
    int*    bucket_cnt = (int*)(ws + off); off += NB;
    int*    srcs       = (int*)(ws + off); off += srcsCap;
    int*    dsts       = (int*)(ws + off); off += srcsCap;
    float*  alphas     = (float*)(ws + off); off += srcsCap;
    int*    blockSums  = (int*)(ws + off); off += 256;

    hipMemsetAsync(deg, 0, (size_t)N * 4, stream);
    hipMemsetAsync(bucket_cnt, 0, (size_t)NB * 4, stream);
    hipMemsetAsync(srcs, 0xFF, srcsCap * 4, stream);   // padding slots = -1

    const int nbN4   = (N + 3) / 4;          // wave-per-node kernels, 4 nodes/block
    const int nbScan = (N + 1023) / 1024;    // <= 256 required by k_scan2
    const int nbBin  = (E + BIN_EPB - 1) / BIN_EPB;
    const int nbCap  = (int)((srcsCap + 255) / 256);

    k_feat<<<(N + 255) / 256, 256, 0, stream>>>(num_prop, cat_prop, W_num, b_num,
                                                W_cat, b_cat, W_tog, b_tog,
                                                att_l, att_r, xb, al, ar, N);

    // radix partition phase 1 (+ deg histogram folded in)
    k_bin<<<nbBin, 256, 0, stream>>>(src, dst, deg, bucket_cnt, buckets, E, NB);

    // padded CSR offsets
    k_scan1<<<nbScan, 1024, 0, stream>>>(deg, row_start, blockSums, N);
    k_scan2<<<1, 256, 0, stream>>>(blockSums, nbScan);
    k_scan3<<<(N + 255) / 256, 256, 0, stream>>>(row_start, blockSums, deg, al, ald1, N);

    // radix partition phase 2: bucket-local CSR fill (LDS cursors)
    k_fill2<<<NB, 1024, 0, stream>>>(buckets, bucket_cnt, row_start, srcs, dsts);

    // ---- FAConv layer 1 (h = h0 = x): edge-parallel alpha, scalar-offload gather
    k_alphaE<<<nbCap, 256, 0, stream>>>(srcs, dsts, ald1, ar, alphas, (int)srcsCap);
    k_gather1<<<nbN4, 256, 0, stream>>>(srcs, alphas, row_start, deg, xb, ald1, ar,
                                        att_l, att_r, h1b, ald2, ar2, N);

    // ---- FAConv layer 2 (h = h1, h0 = x)
    k_alphaE<<<nbCap, 256, 0, stream>>>(srcs, dsts, ald2, ar2, alphas, (int)srcsCap);
    k_gather2<<<nbN4, 256, 0, stream>>>(srcs, alphas, row_start, deg, h1b, xb,
                                        ald2, ar2, B, N);

    // ---- per-user pooling + head ----
    k_usersum<<<U, 64, 0, stream>>>(B, offs, x3, U);
    k_head<<<(U + 255) / 256, 256, 0, stream>>>(x3, re_index, W_f1, b_f1, W_lab, b_lab,
                                                (float*)d_out, U);
}

// Round 12
// 513.131 us; speedup vs baseline: 1.0584x; 1.0584x over previous
//
#include <hip/hip_runtime.h>
#include <hip/hip_bf16.h>

#define LRELU(v) ((v) > 0.0f ? (v) : 0.01f * (v))
#define EPS 0.1f

#define BIN_EPB 2048        // edges per k_bin block
#define BIN_CAP 12288       // bucket capacity (expected 8163, +45 sigma headroom)

// fast tanh via v_exp_f32 + v_rcp_f32: ~1e-7 abs err, saturates correctly
__device__ __forceinline__ float fast_tanh(float v)
{
    float e = __expf(2.0f * v);
    return 1.0f - 2.0f * __builtin_amdgcn_rcpf(e + 1.0f);
}

// bf16 <-> f32 (RNE pack); feature rows stored bf16 to halve gather traffic
__device__ __forceinline__ float bf2f(unsigned short h)
{
    return __uint_as_float(((unsigned int)h) << 16);
}
__device__ __forceinline__ unsigned short f2bf(float f)
{
    unsigned int u = __float_as_uint(f);
    u += 0x7FFFu + ((u >> 16) & 1u);
    return (unsigned short)(u >> 16);
}

// ---------------------------------------------------------------------------
// K1: per-node feature MLP, thread-per-node. Weight accesses wave-uniform ->
// SGPR path; mid[64] in VGPRs; ILP-4 fma chains. Fuses al/ar dots.
// __launch_bounds__(256,2): ~130 live VGPRs; without it the allocator capped
// at 64 VGPRs and spilled ~400 MB to scratch (round-9 regression).
// ---------------------------------------------------------------------------
__global__ void __launch_bounds__(256, 2)
k_feat(const float* __restrict__ num_prop,
       const float* __restrict__ cat_prop,
       const float* __restrict__ W_num, const float* __restrict__ b_num,
       const float* __restrict__ W_cat, const float* __restrict__ b_cat,
       const float* __restrict__ W_tog, const float* __restrict__ b_tog,
       const float* __restrict__ att_l, const float* __restrict__ att_r,
       unsigned short* __restrict__ xb,
       float* __restrict__ al, float* __restrict__ ar, int N)
{
    int n = blockIdx.x * blockDim.x + threadIdx.x;
    if (n >= N) return;

    float num[20], cat[12];
    {
        const float* np_ = num_prop + (size_t)n * 20;
        #pragma unroll
        for (int k = 0; k < 20; k++) num[k] = np_[k];
        const float* cp = cat_prop + (size_t)n * 12;
        #pragma unroll
        for (int k = 0; k < 12; k++) cat[k] = cp[k];
    }

    float mid[64];
    #pragma unroll
    for (int j = 0; j < 32; j++) {
        float s = b_num[j];
        #pragma unroll
        for (int k = 0; k < 20; k++) s = fmaf(num[k], W_num[k * 32 + j], s);
        mid[j] = LRELU(s);
    }
    #pragma unroll
    for (int j = 0; j < 32; j++) {
        float s = b_cat[j];
        #pragma unroll
        for (int k = 0; k < 12; k++) s = fmaf(cat[k], W_cat[k * 32 + j], s);
        mid[32 + j] = LRELU(s);
    }

    float al_acc = 0.0f, ar_acc = 0.0f;
    unsigned short* xbrow = xb + (size_t)n * 64;
    for (int j0 = 0; j0 < 64; j0 += 4) {     // 16 iterations (code size)
        float o[4];
        #pragma unroll
        for (int jj = 0; jj < 4; jj++) {
            int j = j0 + jj;
            float s = b_tog[j];
            #pragma unroll
            for (int k = 0; k < 64; k++) s = fmaf(mid[k], W_tog[k * 64 + j], s);
            s = LRELU(s);
            o[jj] = s;
            al_acc = fmaf(s, att_l[j], al_acc);
            ar_acc = fmaf(s, att_r[j], ar_acc);
        }
        *(ushort4*)(xbrow + j0) = make_ushort4(f2bf(o[0]), f2bf(o[1]),
                                               f2bf(o[2]), f2bf(o[3]));  // ws: aligned
    }
    al[n] = al_acc;
    ar[n] = ar_acc;
}

// ---------------------------------------------------------------------------
// K2: radix partition phase 1. NO global atomics anymore (the folded deg
// histogram was 1.6M random device-scope atomics -> 65 MB write amp and an
// 85 us latency-bound dispatch in round 11; deg now comes from k_degB).
// ---------------------------------------------------------------------------
__global__ void k_bin(const int* __restrict__ src, const int* __restrict__ dst,
                      int* __restrict__ bucket_cnt,
                      int2* __restrict__ buckets, int E, int NB)
{
    __shared__ int  hist[256];
    __shared__ int  lbase[256];
    __shared__ int  gbase[256];
    __shared__ int2 stage[BIN_EPB];

    int tid  = threadIdx.x;          // blockDim = 256
    int base = blockIdx.x * BIN_EPB;

    hist[tid] = 0;
    __syncthreads();

    int s[8], d[8], rk[8];
    #pragma unroll
    for (int k = 0; k < 8; k++) {
        int e = base + k * 256 + tid;
        s[k] = -1;
        if (e < E) {
            s[k] = src[e];
            d[k] = dst[e];
            rk[k] = atomicAdd(&hist[d[k] >> 10], 1);
        }
    }
    __syncthreads();

    int v = hist[tid];
    lbase[tid] = v;
    __syncthreads();
    for (int off = 1; off < 256; off <<= 1) {
        int t = (tid >= off) ? lbase[tid - off] : 0;
        __syncthreads();
        lbase[tid] += t;
        __syncthreads();
    }
    int incl = lbase[tid];
    __syncthreads();
    lbase[tid] = incl - v;
    if (tid < NB && v > 0) gbase[tid] = atomicAdd(&bucket_cnt[tid], v);
    __syncthreads();

    #pragma unroll
    for (int k = 0; k < 8; k++) {
        if (s[k] >= 0) {
            int b = d[k] >> 10;
            stage[lbase[b] + rk[k]] = make_int2(s[k], d[k]);
        }
    }
    __syncthreads();

    int tot = min(BIN_EPB, E - base);
    for (int i = tid; i < tot; i += 256) {
        int2 p = stage[i];
        int b = p.y >> 10;
        buckets[(size_t)b * BIN_CAP + gbase[b] + (i - lbase[b])] = p;
    }
}

// ---------------------------------------------------------------------------
// K2b: per-bucket degree histogram. One block per bucket; LDS counters
// (no global atomics), then one coalesced 4 KB deg write per block.
// ---------------------------------------------------------------------------
__global__ void k_degB(const int2* __restrict__ buckets, const int* __restrict__ bucket_cnt,
                       int* __restrict__ deg, int N)
{
    __shared__ int cur[1024];
    int b   = blockIdx.x;
    int tid = threadIdx.x;          // blockDim = 1024
    cur[tid] = 0;
    __syncthreads();

    int cnt = bucket_cnt[b];
    const int2* bp = buckets + (size_t)b * BIN_CAP;
    for (int i = tid; i < cnt; i += 1024)
        atomicAdd(&cur[bp[i].y & 1023], 1);
    __syncthreads();

    int n = b * 1024 + tid;
    if (n < N) deg[n] = cur[tid];
}

// ---------------------------------------------------------------------------
// CSR scan over PADDED row lengths ((deg+7)&~7).
// ---------------------------------------------------------------------------
__global__ void k_scan1(const int* __restrict__ deg, int* __restrict__ row_start,
                        int* __restrict__ blockSums, int N)
{
    __shared__ int sh[1024];
    int tid = threadIdx.x;
    int i = blockIdx.x * 1024 + tid;
    int v = (i < N) ? ((deg[i] + 7) & ~7) : 0;      // padded length
    sh[tid] = v;
    __syncthreads();
    #pragma unroll
    for (int off = 1; off < 1024; off <<= 1) {
        int t = (tid >= off) ? sh[tid - off] : 0;
        __syncthreads();
        sh[tid] += t;
        __syncthreads();
    }
    if (i < N) row_start[i] = sh[tid] - v;          // exclusive within block
    if (tid == 1023) blockSums[blockIdx.x] = sh[1023];
}

__global__ void k_scan2(int* __restrict__ blockSums, int nb)
{
    __shared__ int sh[256];
    int tid = threadIdx.x;
    int v = (tid < nb) ? blockSums[tid] : 0;
    sh[tid] = v;
    __syncthreads();
    #pragma unroll
    for (int off = 1; off < 256; off <<= 1) {
        int t = (tid >= off) ? sh[tid - off] : 0;
        __syncthreads();
        sh[tid] += t;
        __syncthreads();
    }
    if (tid < nb) blockSums[tid] = sh[tid] - v;     // exclusive
}

// row_start += block offset; pack ald1 = {al, rsqrt(deg+1)}
__global__ void k_scan3(int* __restrict__ row_start, const int* __restrict__ blockSums,
                        const int* __restrict__ deg,
                        const float* __restrict__ al, float2* __restrict__ ald1, int N)
{
    int i = blockIdx.x * blockDim.x + threadIdx.x;
    if (i >= N) return;
    row_start[i] += blockSums[i >> 10];
    float dv = 1.0f / sqrtf((float)deg[i] + 1.0f);   // +1 self-loop
    ald1[i]  = make_float2(al[i], dv);
}

// ---------------------------------------------------------------------------
// K4: radix partition phase 2: bucket-local CSR fill (LDS cursors). Also
// stores dsts[] (for the layer-2 alpha pass) and computes layer-1 alpha
// inline (ald1 is ready; ar[d]/ald[d] are bucket-local and L1-warm).
// Padding alphas slots are pre-memset to 0.
// ---------------------------------------------------------------------------
__global__ void k_fill2(const int2* __restrict__ buckets, const int* __restrict__ bucket_cnt,
                        const int* __restrict__ row_start,
                        const float2* __restrict__ ald, const float* __restrict__ arr,
                        int* __restrict__ srcs, int* __restrict__ dsts,
                        float* __restrict__ alphas)
{
    __shared__ int cur[1024];
    int b   = blockIdx.x;
    int tid = threadIdx.x;          // blockDim = 1024
    cur[tid] = 0;
    __syncthreads();

    int cnt = bucket_cnt[b];
    const int2* bp = buckets + (size_t)b * BIN_CAP;
    for (int i = tid; i < cnt; i += 1024) {
        int2 p = bp[i];
        int r = p.y & 1023;
        int o = atomicAdd(&cur[r], 1);
        int pos = row_start[p.y] + o;
        float2 as = ald[p.x];           // random 8B (L2/L3)
        float2 ad = ald[p.y];           // bucket-local
        srcs[pos]   = p.x;
        dsts[pos]   = p.y;
        alphas[pos] = fast_tanh(as.x + arr[p.y]) * as.y * ad.y;
    }
}

// ---------------------------------------------------------------------------
// K4b: edge-parallel alpha in CSR order (layer 2 only; layer 1 is fused into
// k_fill2). Padding slots (src = -1) get alpha = 0; dsts never read there.
// ---------------------------------------------------------------------------
__global__ void k_alphaE(const int* __restrict__ srcs, const int* __restrict__ dsts,
                         const float2* __restrict__ ald, const float* __restrict__ arr,
                         float* __restrict__ alphas, int P)
{
    int p = blockIdx.x * blockDim.x + threadIdx.x;
    if (p >= P) return;
    int s = srcs[p];
    float a = 0.0f;
    if (s >= 0) {
        int d = dsts[p];
        float2 as = ald[s];
        float2 ad = ald[d];
        a = fast_tanh(as.x + arr[d]) * as.y * ad.y;
    }
    alphas[p] = a;
}

// ---------------------------------------------------------------------------
// K5: gather layer 1. n is readfirstlane'd -> wave-uniform: srcs/alphas loads
// become s_load (scalar pipe), row address arith is SALU, per-edge VALU is
// load+cvt+fma with alpha as the fma's SGPR operand. Rows padded to x8.
// Fused finalize + al2/ar2 reductions; epilogue packs ald2 = {al2, dinv}.
// ---------------------------------------------------------------------------
__global__ void k_gather1(const int* __restrict__ srcs, const float* __restrict__ alphas,
                          const int* __restrict__ row_start, const int* __restrict__ deg,
                          const unsigned short* __restrict__ xb,
                          const float2* __restrict__ ald1, const float* __restrict__ ar,
                          const float* __restrict__ att_l, const float* __restrict__ att_r,
                          unsigned short* __restrict__ h1b, float2* __restrict__ ald2,
                          float* __restrict__ ar2, int N)
{
    int lane = threadIdx.x & 63;
    int n    = __builtin_amdgcn_readfirstlane(blockIdx.x * 4 + (threadIdx.x >> 6));
    if (n >= N) return;

    int    s0   = row_start[n];
    int    cnt  = deg[n];
    int    cntp = (cnt + 7) & ~7;
    float2 self = ald1[n];          // {al[n], dinv[n]}
    float  di   = self.y;
    float  arn  = ar[n];

    float acc = 0.0f;
    for (int j = 0; j < cntp; j += 8) {
        int sv[8]; float av[8], vv[8];
        #pragma unroll
        for (int t = 0; t < 8; t++) {
            sv[t] = max(srcs[s0 + j + t], 0);     // scalar: padding -> row 0
            av[t] = alphas[s0 + j + t];           // scalar: padding -> 0
        }
        #pragma unroll
        for (int t = 0; t < 8; t++) vv[t] = bf2f(xb[(size_t)sv[t] * 64 + lane]);
        #pragma unroll
        for (int t = 0; t < 8; t++) acc = fmaf(vv[t], av[t], acc);
    }

    float selfa = fast_tanh(self.x + arn) * di * di;
    float xnl   = bf2f(xb[(size_t)n * 64 + lane]);
    float v     = acc + (selfa + EPS) * xnl;

    float pl = v * att_l[lane];
    float pr = v * att_r[lane];
    #pragma unroll
    for (int off = 32; off > 0; off >>= 1) {
        pl += __shfl_down(pl, off);
        pr += __shfl_down(pr, off);
    }
    h1b[(size_t)n * 64 + lane] = f2bf(v);
    if (lane == 0) { ald2[n] = make_float2(pl, di); ar2[n] = pr; }
}

// ---------------------------------------------------------------------------
// K6: gather layer 2 (h = h1 bf16, h0 = x bf16), same scalar-offload
// structure, fused finalize + abs-smooth; x2 written fp32.
// ---------------------------------------------------------------------------
__global__ void k_gather2(const int* __restrict__ srcs, const float* __restrict__ alphas,
                          const int* __restrict__ row_start, const int* __restrict__ deg,
                          const unsigned short* __restrict__ h1b,
                          const unsigned short* __restrict__ xb,
                          const float2* __restrict__ ald2, const float* __restrict__ ar2,
                          float* __restrict__ x2, int N)
{
    int lane = threadIdx.x & 63;
    int n    = __builtin_amdgcn_readfirstlane(blockIdx.x * 4 + (threadIdx.x >> 6));
    if (n >= N) return;

    int    s0   = row_start[n];
    int    cnt  = deg[n];
    int    cntp = (cnt + 7) & ~7;
    float2 self = ald2[n];          // {al2[n], dinv[n]}
    float  di   = self.y;
    float  arn  = ar2[n];

    float acc = 0.0f;
    for (int j = 0; j < cntp; j += 8) {
        int sv[8]; float av[8], vv[8];
        #pragma unroll
        for (int t = 0; t < 8; t++) {
            sv[t] = max(srcs[s0 + j + t], 0);
            av[t] = alphas[s0 + j + t];
        }
        #pragma unroll
        for (int t = 0; t < 8; t++) vv[t] = bf2f(h1b[(size_t)sv[t] * 64 + lane]);
        #pragma unroll
        for (int t = 0; t < 8; t++) acc = fmaf(vv[t], av[t], acc);
    }

    float selfa = fast_tanh(self.x + arn) * di * di;
    float h1l   = bf2f(h1b[(size_t)n * 64 + lane]);
    float xnl   = bf2f(xb[(size_t)n * 64 + lane]);
    float v = acc + selfa * h1l + EPS * xnl;
    x2[(size_t)n * 64 + lane] = sqrtf(v * v + 1e-8f);
}

// ---------------------------------------------------------------------------
// K7: per-user CSR segment sum
// ---------------------------------------------------------------------------
__global__ void k_usersum(const float* __restrict__ x2, const int* __restrict__ offs,
                          float* __restrict__ x3, int U)
{
    int u    = blockIdx.x;
    int lane = threadIdx.x;
    if (u >= U) return;
    int s = offs[u], e = offs[u + 1];
    float acc = 0.0f;
    for (int n = s; n < e; n++) acc += x2[(size_t)n * 64 + lane];
    x3[(size_t)u * 64 + lane] = acc;
}

// ---------------------------------------------------------------------------
// K8: head
// ---------------------------------------------------------------------------
__global__ void k_head(const float* __restrict__ x3, const int* __restrict__ re_index,
                       const float* __restrict__ W_f1, const float* __restrict__ b_f1,
                       const float* __restrict__ W_lab, const float* __restrict__ b_lab,
                       float* __restrict__ out, int U)
{
    int u = blockIdx.x * blockDim.x + threadIdx.x;
    if (u >= U) return;
    int r = re_index[u];
    const float* y = x3 + (size_t)r * 64;
    float yv[64];
    #pragma unroll
    for (int k = 0; k < 64; k++) yv[k] = y[k];
    float o0 = b_lab[0], o1 = b_lab[1];
    for (int j = 0; j < 32; j++) {
        float s = b_f1[j];
        #pragma unroll 8
        for (int k = 0; k < 64; k++) s = fmaf(yv[k], W_f1[k * 32 + j], s);
        s = LRELU(s);
        o0 = fmaf(s, W_lab[j * 2 + 0], o0);
        o1 = fmaf(s, W_lab[j * 2 + 1], o1);
    }
    out[(size_t)u * 2 + 0] = o0;
    out[(size_t)u * 2 + 1] = o1;
}

// ---------------------------------------------------------------------------
extern "C" void kernel_launch(void* const* d_in, const int* in_sizes, int n_in,
                              void* d_out, int out_size, void* d_ws, size_t ws_size,
                              hipStream_t stream)
{
    const float* num_prop = (const float*)d_in[0];
    const float* cat_prop = (const float*)d_in[1];
    const int*   offs     = (const int*)d_in[2];
    const int*   edge     = (const int*)d_in[3];
    const int*   re_index = (const int*)d_in[4];
    const float* W_num    = (const float*)d_in[5];
    const float* b_num    = (const float*)d_in[6];
    const float* W_cat    = (const float*)d_in[7];
    const float* b_cat    = (const float*)d_in[8];
    const float* W_tog    = (const float*)d_in[9];
    const float* b_tog    = (const float*)d_in[10];
    const float* att_l    = (const float*)d_in[11];
    const float* att_r    = (const float*)d_in[12];
    const float* W_f1     = (const float*)d_in[13];
    const float* b_f1     = (const float*)d_in[14];
    const float* W_lab    = (const float*)d_in[15];
    const float* b_lab    = (const float*)d_in[16];

    const int N = in_sizes[0] / 20;
    const int E = in_sizes[3] / 2;
    const int U = in_sizes[4];

    const int* src = edge;       // edge_index[0]
    const int* dst = edge + E;   // edge_index[1]

    const int    NB      = (N + 1023) >> 10;                   // dst buckets
    const size_t srcsCap = (size_t)E + 7ull * (size_t)N + 64;  // padded CSR capacity

    // workspace carve-up (4-byte units; int2/float2/ushort4 8B-aligned by layout)
    float* ws = (float*)d_ws;
    size_t off = 0;
    unsigned short* xb  = (unsigned short*)(ws + off); off += (size_t)N * 32;  // bf16 x
    unsigned short* h1b = (unsigned short*)(ws + off); off += (size_t)N * 32;  // bf16 h1
    float*  B    = ws + off; off += (size_t)N * 64;   // x2 (fp32)
    float2* ald1 = (float2*)(ws + off); off += (size_t)N * 2;
    float2* ald2 = (float2*)(ws + off); off += (size_t)N * 2;
    int2*   buckets = (int2*)(ws + off); off += (size_t)NB * BIN_CAP * 2;
    float*  al   = ws + off; off += N;
    float*  ar   = ws + off; off += N;
    float*  ar2  = ws + off; off += N;
    float*  x3   = ws + off; off += (size_t)U * 64;
    int*    deg        = (int*)(ws + off); off += N;
    int*    row_start  = (int*)(ws + off); off += N;
    int*    bucket_cnt = (int*)(ws + off); off += NB;
    int*    srcs       = (int*)(ws + off); off += srcsCap;
    int*    dsts       = (int*)(ws + off); off += srcsCap;
    float*  alphas     = (float*)(ws + off); off += srcsCap;
    int*    blockSums  = (int*)(ws + off); off += 256;

    hipMemsetAsync(bucket_cnt, 0, (size_t)NB * 4, stream);
    hipMemsetAsync(srcs, 0xFF, srcsCap * 4, stream);   // padding slots = -1
    hipMemsetAsync(alphas, 0, srcsCap * 4, stream);    // padding alphas = 0

    const int nbN4   = (N + 3) / 4;          // wave-per-node kernels, 4 nodes/block
    const int nbScan = (N + 1023) / 1024;    // <= 256 required by k_scan2
    const int nbBin  = (E + BIN_EPB - 1) / BIN_EPB;
    const int nbCap  = (int)((srcsCap + 255) / 256);

    k_feat<<<(N + 255) / 256, 256, 0, stream>>>(num_prop, cat_prop, W_num, b_num,
                                                W_cat, b_cat, W_tog, b_tog,
                                                att_l, att_r, xb, al, ar, N);

    // radix partition phase 1 (no global atomics)
    k_bin<<<nbBin, 256, 0, stream>>>(src, dst, bucket_cnt, buckets, E, NB);

    // per-bucket degree histogram (LDS counters, coalesced deg write)
    k_degB<<<NB, 1024, 0, stream>>>(buckets, bucket_cnt, deg, N);

    // padded CSR offsets
    k_scan1<<<nbScan, 1024, 0, stream>>>(deg, row_start, blockSums, N);
    k_scan2<<<1, 256, 0, stream>>>(blockSums, nbScan);
    k_scan3<<<(N + 255) / 256, 256, 0, stream>>>(row_start, blockSums, deg, al, ald1, N);

    // radix partition phase 2: bucket-local CSR fill + fused layer-1 alpha
    k_fill2<<<NB, 1024, 0, stream>>>(buckets, bucket_cnt, row_start, ald1, ar,
                                     srcs, dsts, alphas);

    // ---- FAConv layer 1 (h = h0 = x): scalar-offload gather ----
    k_gather1<<<nbN4, 256, 0, stream>>>(srcs, alphas, row_start, deg, xb, ald1, ar,
                                        att_l, att_r, h1b, ald2, ar2, N);

    // ---- FAConv layer 2 (h = h1, h0 = x) ----
    k_alphaE<<<nbCap, 256, 0, stream>>>(srcs, dsts, ald2, ar2, alphas, (int)srcsCap);
    k_gather2<<<nbN4, 256, 0, stream>>>(srcs, alphas, row_start, deg, h1b, xb,
                                        ald2, ar2, B, N);

    // ---- per-user pooling + head ----
    k_usersum<<<U, 64, 0, stream>>>(B, offs, x3, U);
    k_head<<<(U + 255) / 256, 256, 0, stream>>>(x3, re_index, W_f1, b_f1, W_lab, b_lab,
                                                (float*)d_out, U);
}